// Round 1
// baseline (684.789 us; speedup 1.0000x reference)
//
#include <hip/hip_runtime.h>

// Problem constants
#define Bc   32
#define TGTc 512
#define SRCc 2048
#define Hc   512

typedef unsigned short u16;
typedef unsigned int   u32;
typedef __attribute__((ext_vector_type(8))) short s16x8;
typedef __attribute__((ext_vector_type(4))) float f32x4;
typedef __attribute__((ext_vector_type(4))) unsigned short u16x4;

__device__ __forceinline__ u16 f2bf(float x) {
    u32 u = __float_as_uint(x);
    u32 r = (u + 0x7FFFu + ((u >> 16) & 1u)) >> 16;
    return (u16)r;
}
__device__ __forceinline__ float bf2f(u16 h) {
    return __uint_as_float(((u32)h) << 16);
}

// ---------------- prep kernels ----------------

// lengths may be int64 (jax x64) or int32; detect via high word of elem 0
__global__ void prep_len_k(const u32* __restrict__ raw, int* __restrict__ out) {
    int i = threadIdx.x;
    if (i >= Bc) return;
    bool is64 = (raw[1] == 0u);   // lengths >= 1024, so int32 path has raw[1] != 0
    out[i] = (int)(is64 ? raw[2 * i] : raw[i]);
}

// split fp32 -> bf16 hi + bf16 lo, vectorized x4
__global__ __launch_bounds__(256) void split_k(const float* __restrict__ in,
                                               u16* __restrict__ hi, u16* __restrict__ lo,
                                               int n4) {
    int stride = gridDim.x * 256;
    for (int i = blockIdx.x * 256 + threadIdx.x; i < n4; i += stride) {
        f32x4 x = ((const f32x4*)in)[i];
        u16x4 h, l;
#pragma unroll
        for (int j = 0; j < 4; j++) {
            u16 hb = f2bf(x[j]);
            h[j] = hb;
            l[j] = f2bf(x[j] - bf2f(hb));
        }
        ((u16x4*)hi)[i] = h;
        ((u16x4*)lo)[i] = l;
    }
}

// W_out [512][1024] -> A half (cols 0..511) and B half (cols 512..1023), hi/lo each
__global__ __launch_bounds__(256) void split_wout_k(const float* __restrict__ in,
                                                    u16* __restrict__ ah, u16* __restrict__ al,
                                                    u16* __restrict__ bh, u16* __restrict__ bl) {
    int i = blockIdx.x * 256 + threadIdx.x;   // over 512*1024/4 = 131072 float4s
    if (i >= 512 * 256) return;
    int o = i >> 8, kc = i & 255;
    f32x4 x = ((const f32x4*)in)[i];
    u16x4 h, l;
#pragma unroll
    for (int j = 0; j < 4; j++) {
        u16 hb = f2bf(x[j]);
        h[j] = hb;
        l[j] = f2bf(x[j] - bf2f(hb));
    }
    int half = kc >> 7;
    int idx = o * 128 + (kc & 127);
    ((u16x4*)(half ? bh : ah))[idx] = h;
    ((u16x4*)(half ? bl : al))[idx] = l;
}

// enc [B][SRC][H] fp32 -> enc_hi/lo [B][SRC][H] bf16 and encT_hi [B][H][SRC] bf16
__global__ __launch_bounds__(256) void prep_enc_k(const float* __restrict__ enc,
                                                  u16* __restrict__ ehi, u16* __restrict__ elo,
                                                  u16* __restrict__ ethi) {
    __shared__ float tile[32][33];
    const int b = blockIdx.z;
    const int s0 = blockIdx.x << 5, h0 = blockIdx.y << 5;
    const int x = threadIdx.x & 31, y = threadIdx.x >> 5;   // y in 0..7
    const long base = ((long)b * SRCc + s0) * Hc + h0;
#pragma unroll
    for (int j = 0; j < 4; j++) {
        int s = (y << 2) + j;
        float v = enc[base + (long)s * Hc + x];
        tile[s][x] = v;
        u16 h = f2bf(v);
        long o = base + (long)s * Hc + x;
        ehi[o] = h;
        elo[o] = f2bf(v - bf2f(h));
    }
    __syncthreads();
    const long tbase = ((long)b * Hc + h0) * SRCc + s0;
#pragma unroll
    for (int j = 0; j < 4; j++) {
        int hh = (y << 2) + j;
        float v = tile[x][hh];
        long o = tbase + (long)hh * SRCc + x;
        ethi[o] = f2bf(v);
    }
}

// ---------------- GEMM template ----------------
// C = sum_combos A_i [M][K] * B_j [N][K]^T, all bf16 row-major K-contiguous.
// 128x128 tile, BK=32, 256 threads = 4 waves (2x2), each wave 64x64 = 4x4 frags of 16x16x32.
// CFG 0: q GEMM        A={dec_hi,dec_lo} B={win_hi,win_lo} combos 3, K=512  -> split-store q
// CFG 1: align GEMM    A={q_hi,q_lo}     B={enc_hi,enc_lo} combos 3, K=512  -> f32 logits [t][b][s]
// CFG 2: PV GEMM       A={Pb}            B={encT_hi}       combos 1, K=2048 -> split-store ctx
// CFG 3: out GEMM a    A={ctx_hi,ctx_lo} B={wA_hi,wA_lo}   combos 3, K=512  -> f32 partial
// CFG 4: out GEMM b    A={dec_hi,dec_lo} B={wB_hi,wB_lo}   combos 3, K=512  -> +partial, tanh, [t][b][o]

struct GArgs {
    const u16* A0; const u16* A1;
    const u16* B0; const u16* B1;
    void* out0; void* out1;
    const float* aux;
};

__device__ __forceinline__ void gload_lds16(const u16* g, u16* l) {
    __builtin_amdgcn_global_load_lds((const __attribute__((address_space(1))) void*)g,
                                     (__attribute__((address_space(3))) void*)l, 16, 0, 0);
}

template <int CFG>
__global__ __launch_bounds__(256, 2) void gemm_bt(GArgs g) {
    constexpr int NA = (CFG == 2) ? 1 : 2;
    constexpr int NB = (CFG == 2) ? 1 : 2;
    constexpr int NC = (CFG == 2) ? 1 : 3;
    constexpr int K  = (CFG == 2) ? 2048 : 512;
    constexpr int NT = NA + NB;

    __shared__ u16 lds[NT * 128 * 32];

    const int tid = threadIdx.x;
    const int lane = tid & 63;
    const int wave = tid >> 6;
    const int wm = wave >> 1;
    const int wn = wave & 1;

    int bz = 0, mt, nt;
    if constexpr (CFG == 1 || CFG == 2) { bz = blockIdx.x; mt = blockIdx.y; nt = blockIdx.z; }
    else { mt = blockIdx.x; nt = blockIdx.y; }

    const u16* ap[NA];
    const u16* bp[NB];
    if constexpr (CFG == 1) {
        const long ao = (long)bz * TGTc * Hc, bo = (long)bz * SRCc * Hc;
        ap[0] = g.A0 + ao; ap[1] = g.A1 + ao;
        bp[0] = g.B0 + bo; bp[1] = g.B1 + bo;
    } else if constexpr (CFG == 2) {
        ap[0] = g.A0 + (long)bz * TGTc * SRCc;
        bp[0] = g.B0 + (long)bz * Hc * SRCc;
    } else {
        ap[0] = g.A0; ap[1] = g.A1;
        bp[0] = g.B0; bp[1] = g.B1;
    }

    f32x4 acc[4][4];
#pragma unroll
    for (int mi = 0; mi < 4; mi++)
#pragma unroll
        for (int ni = 0; ni < 4; ni++)
            acc[mi][ni] = (f32x4){0.f, 0.f, 0.f, 0.f};

    const int arow0 = mt * 128;
    const int brow0 = nt * 128;

    constexpr int cAi[3] = {0, 0, 1};
    constexpr int cBi[3] = {0, 1, 0};

    for (int k0 = 0; k0 < K; k0 += 32) {
        // stage NT tiles of 128x32 bf16 (8 KB each) via global_load_lds width 16
#pragma unroll
        for (int t = 0; t < NT; t++) {
            const u16* src = (t < NA) ? (ap[t] + (long)arow0 * K + k0)
                                      : (bp[t - NA] + (long)brow0 * K + k0);
            u16* dstbase = &lds[t * 4096];
#pragma unroll
            for (int it = 0; it < 2; ++it) {
                int l = it * 256 + tid;
                int row = l >> 2;
                int kel = (l & 3) << 3;
                // LDS dest must be wave-uniform: base + it*2048 + wave*512 (u16 units);
                // HW adds lane*16B. Global src is per-lane.
                gload_lds16(src + row * K + kel, dstbase + it * 2048 + wave * 512);
            }
        }
        __syncthreads();

        s16x8 af[NA][4];
        s16x8 bfr[NB][4];
#pragma unroll
        for (int i = 0; i < NA; i++)
#pragma unroll
            for (int f = 0; f < 4; f++) {
                int r = wm * 64 + f * 16 + (lane & 15);
                af[i][f] = *(const s16x8*)&lds[i * 4096 + r * 32 + ((lane >> 4) << 3)];
            }
#pragma unroll
        for (int i = 0; i < NB; i++)
#pragma unroll
            for (int f = 0; f < 4; f++) {
                int r = wn * 64 + f * 16 + (lane & 15);
                bfr[i][f] = *(const s16x8*)&lds[(NA + i) * 4096 + r * 32 + ((lane >> 4) << 3)];
            }

#pragma unroll
        for (int c = 0; c < NC; c++)
#pragma unroll
            for (int mi = 0; mi < 4; mi++)
#pragma unroll
                for (int ni = 0; ni < 4; ni++)
                    acc[mi][ni] = __builtin_amdgcn_mfma_f32_16x16x32_bf16(
                        af[cAi[c]][mi], bfr[cBi[c]][ni], acc[mi][ni], 0, 0, 0);
        __syncthreads();
    }

    // epilogue; C/D layout: col = lane&15, row = (lane>>4)*4 + j
    const int m0 = mt * 128 + wm * 64;
    const int n0 = nt * 128 + wn * 64;
    const int ln15 = lane & 15;
    const int rg = (lane >> 4) << 2;

#pragma unroll
    for (int mi = 0; mi < 4; mi++) {
#pragma unroll
        for (int ni = 0; ni < 4; ni++) {
            f32x4 v = acc[mi][ni];
            int n = n0 + ni * 16 + ln15;
#pragma unroll
            for (int j = 0; j < 4; j++) {
                int m = m0 + mi * 16 + rg + j;
                float x = v[j];
                if constexpr (CFG == 0) {
                    long idx = (long)m * Hc + n;
                    u16 h = f2bf(x);
                    ((u16*)g.out0)[idx] = h;
                    ((u16*)g.out1)[idx] = f2bf(x - bf2f(h));
                } else if constexpr (CFG == 1) {
                    ((float*)g.out0)[((long)m * Bc + bz) * SRCc + n] = x;
                } else if constexpr (CFG == 2) {
                    long idx = ((long)bz * TGTc + m) * Hc + n;
                    u16 h = f2bf(x);
                    ((u16*)g.out0)[idx] = h;
                    ((u16*)g.out1)[idx] = f2bf(x - bf2f(h));
                } else if constexpr (CFG == 3) {
                    ((float*)g.out0)[(long)m * Hc + n] = x;
                } else {
                    float s = x + g.aux[(long)m * Hc + n];
                    float th = tanhf(s);
                    int t = m & (TGTc - 1), b = m >> 9;
                    ((float*)g.out0)[((long)t * Bc + b) * Hc + n] = th;
                }
            }
        }
    }
}

// ---------------- softmax ----------------
// one block per (b,t) row of 2048; in-place on logits in d_out ([t][b][s]); also writes Pb bf16 [b][t][s]
__global__ __launch_bounds__(256) void softmax_k(float* __restrict__ align, u16* __restrict__ Pb,
                                                 const int* __restrict__ lens) {
    const int row = blockIdx.x;          // b*512 + t
    const int b = row >> 9, t = row & (TGTc - 1);
    float* p = align + ((long)t * Bc + b) * SRCc;
    u16* pb = Pb + ((long)b * TGTc + t) * SRCc;
    const int len = lens[b];
    const int tid = threadIdx.x;

    f32x4 v[2];
    float mx = -3.4e38f;
#pragma unroll
    for (int i = 0; i < 2; i++) {
        int s0 = i * 1024 + tid * 4;
        v[i] = *(const f32x4*)&p[s0];
#pragma unroll
        for (int j = 0; j < 4; j++) {
            if (s0 + j >= len) v[i][j] = -3.4e38f;
            mx = fmaxf(mx, v[i][j]);
        }
    }
#pragma unroll
    for (int o = 32; o >= 1; o >>= 1) mx = fmaxf(mx, __shfl_xor(mx, o));
    __shared__ float red[8];
    if ((tid & 63) == 0) red[tid >> 6] = mx;
    __syncthreads();
    mx = fmaxf(fmaxf(red[0], red[1]), fmaxf(red[2], red[3]));

    float sum = 0.f;
    f32x4 e[2];
#pragma unroll
    for (int i = 0; i < 2; i++) {
        int s0 = i * 1024 + tid * 4;
#pragma unroll
        for (int j = 0; j < 4; j++) {
            float ev = (s0 + j >= len) ? 0.f : __expf(v[i][j] - mx);
            e[i][j] = ev;
            sum += ev;
        }
    }
#pragma unroll
    for (int o = 32; o >= 1; o >>= 1) sum += __shfl_xor(sum, o);
    if ((tid & 63) == 0) red[4 + (tid >> 6)] = sum;
    __syncthreads();
    sum = (red[4] + red[5]) + (red[6] + red[7]);
    float inv = 1.f / sum;

#pragma unroll
    for (int i = 0; i < 2; i++) {
        int s0 = i * 1024 + tid * 4;
        f32x4 o4;
        u16x4 h4;
#pragma unroll
        for (int j = 0; j < 4; j++) {
            float pv = e[i][j] * inv;
            o4[j] = pv;
            h4[j] = f2bf(pv);
        }
        *(f32x4*)&p[s0] = o4;
        *(u16x4*)&pb[s0] = h4;
    }
}

// ---------------- launch ----------------

extern "C" void kernel_launch(void* const* d_in, const int* in_sizes, int n_in,
                              void* d_out, int out_size, void* d_ws, size_t ws_size,
                              hipStream_t stream) {
    const float* dec  = (const float*)d_in[0];
    const float* enc  = (const float*)d_in[1];
    const u32*   lenp = (const u32*)d_in[2];
    const float* win  = (const float*)d_in[3];
    const float* wout = (const float*)d_in[4];

    float* out_attn  = (float*)d_out;                          // [512][32][512]
    float* out_align = out_attn + (size_t)TGTc * Bc * Hc;      // [512][32][2048]

    char* w = (char*)d_ws;
    auto take = [&](size_t n) { char* p = w; w += (n + 255) & ~(size_t)255; return p; };
    int* lens      = (int*)take(256);
    u16* dec_hi    = (u16*)take((size_t)8388608 * 2);
    u16* dec_lo    = (u16*)take((size_t)8388608 * 2);
    u16* win_hi    = (u16*)take((size_t)262144 * 2);
    u16* win_lo    = (u16*)take((size_t)262144 * 2);
    u16* wA_hi     = (u16*)take((size_t)262144 * 2);
    u16* wA_lo     = (u16*)take((size_t)262144 * 2);
    u16* wB_hi     = (u16*)take((size_t)262144 * 2);
    u16* wB_lo     = (u16*)take((size_t)262144 * 2);
    float* partial = (float*)take((size_t)8388608 * 4);
    u16* enc_hi    = (u16*)take((size_t)33554432 * 2);   // reused as Pb after K2
    u16* enc_lo    = (u16*)take((size_t)33554432 * 2);   // reused as ctx_hi/lo after K2
    u16* encT_hi   = (u16*)take((size_t)33554432 * 2);
    // aliases (lifetimes disjoint, same stream => ordered)
    u16* q_hi   = (u16*)out_attn;            // attn region free until final kernel
    u16* q_lo   = q_hi + 8388608;
    u16* Pb     = enc_hi;
    u16* ctx_hi = enc_lo;
    u16* ctx_lo = enc_lo + 8388608;
    (void)in_sizes; (void)n_in; (void)out_size; (void)ws_size;

    prep_len_k<<<1, 64, 0, stream>>>(lenp, lens);
    split_k<<<2048, 256, 0, stream>>>(dec, dec_hi, dec_lo, 8388608 / 4);
    split_k<<<256, 256, 0, stream>>>(win, win_hi, win_lo, 262144 / 4);
    split_wout_k<<<512, 256, 0, stream>>>(wout, wA_hi, wA_lo, wB_hi, wB_lo);
    prep_enc_k<<<dim3(64, 16, 32), 256, 0, stream>>>(enc, enc_hi, enc_lo, encT_hi);

    GArgs a1 = {};
    a1.A0 = dec_hi; a1.A1 = dec_lo; a1.B0 = win_hi; a1.B1 = win_lo;
    a1.out0 = q_hi; a1.out1 = q_lo;
    gemm_bt<0><<<dim3(128, 4, 1), 256, 0, stream>>>(a1);

    GArgs a2 = {};
    a2.A0 = q_hi; a2.A1 = q_lo; a2.B0 = enc_hi; a2.B1 = enc_lo;
    a2.out0 = out_align;
    gemm_bt<1><<<dim3(32, 4, 16), 256, 0, stream>>>(a2);

    softmax_k<<<16384, 256, 0, stream>>>(out_align, Pb, lens);

    GArgs a4 = {};
    a4.A0 = Pb; a4.B0 = encT_hi;
    a4.out0 = ctx_hi; a4.out1 = ctx_lo;
    gemm_bt<2><<<dim3(32, 4, 4), 256, 0, stream>>>(a4);

    GArgs a5 = {};
    a5.A0 = ctx_hi; a5.A1 = ctx_lo; a5.B0 = wA_hi; a5.B1 = wA_lo;
    a5.out0 = partial;
    gemm_bt<3><<<dim3(128, 4, 1), 256, 0, stream>>>(a5);

    GArgs a6 = {};
    a6.A0 = dec_hi; a6.A1 = dec_lo; a6.B0 = wB_hi; a6.B1 = wB_lo;
    a6.out0 = out_attn; a6.aux = partial;
    gemm_bt<4><<<dim3(128, 4, 1), 256, 0, stream>>>(a6);
}

// Round 2
// 671.846 us; speedup vs baseline: 1.0193x; 1.0193x over previous
//
#include <hip/hip_runtime.h>

// Problem constants
#define Bc   32
#define TGTc 512
#define SRCc 2048
#define Hc   512

typedef unsigned short u16;
typedef unsigned int   u32;
typedef __attribute__((ext_vector_type(8))) short s16x8;
typedef __attribute__((ext_vector_type(4))) float f32x4;
typedef __attribute__((ext_vector_type(4))) unsigned short u16x4;

__device__ __forceinline__ u16 f2bf(float x) {
    u32 u = __float_as_uint(x);
    u32 r = (u + 0x7FFFu + ((u >> 16) & 1u)) >> 16;
    return (u16)r;
}
__device__ __forceinline__ float bf2f(u16 h) {
    return __uint_as_float(((u32)h) << 16);
}

// ---------------- prep kernels ----------------

// lengths may be int64 (jax x64) or int32; detect via high word of elem 0
__global__ void prep_len_k(const u32* __restrict__ raw, int* __restrict__ out) {
    int i = threadIdx.x;
    if (i >= Bc) return;
    bool is64 = (raw[1] == 0u);   // lengths >= 1024, so int32 path has raw[1] != 0
    out[i] = (int)(is64 ? raw[2 * i] : raw[i]);
}

// split fp32 -> bf16 hi + bf16 lo, vectorized x4
__global__ __launch_bounds__(256) void split_k(const float* __restrict__ in,
                                               u16* __restrict__ hi, u16* __restrict__ lo,
                                               int n4) {
    int stride = gridDim.x * 256;
    for (int i = blockIdx.x * 256 + threadIdx.x; i < n4; i += stride) {
        f32x4 x = ((const f32x4*)in)[i];
        u16x4 h, l;
#pragma unroll
        for (int j = 0; j < 4; j++) {
            u16 hb = f2bf(x[j]);
            h[j] = hb;
            l[j] = f2bf(x[j] - bf2f(hb));
        }
        ((u16x4*)hi)[i] = h;
        ((u16x4*)lo)[i] = l;
    }
}

// W_out [512][1024] -> A half (cols 0..511) and B half (cols 512..1023), hi/lo each
__global__ __launch_bounds__(256) void split_wout_k(const float* __restrict__ in,
                                                    u16* __restrict__ ah, u16* __restrict__ al,
                                                    u16* __restrict__ bh, u16* __restrict__ bl) {
    int i = blockIdx.x * 256 + threadIdx.x;   // over 512*1024/4 = 131072 float4s
    if (i >= 512 * 256) return;
    int o = i >> 8, kc = i & 255;
    f32x4 x = ((const f32x4*)in)[i];
    u16x4 h, l;
#pragma unroll
    for (int j = 0; j < 4; j++) {
        u16 hb = f2bf(x[j]);
        h[j] = hb;
        l[j] = f2bf(x[j] - bf2f(hb));
    }
    int half = kc >> 7;
    int idx = o * 128 + (kc & 127);
    ((u16x4*)(half ? bh : ah))[idx] = h;
    ((u16x4*)(half ? bl : al))[idx] = l;
}

// enc [B][SRC][H] fp32 -> enc_hi/lo [B][SRC][H] bf16 and encT_hi [B][H][SRC] bf16
__global__ __launch_bounds__(256) void prep_enc_k(const float* __restrict__ enc,
                                                  u16* __restrict__ ehi, u16* __restrict__ elo,
                                                  u16* __restrict__ ethi) {
    __shared__ float tile[32][33];
    const int b = blockIdx.z;
    const int s0 = blockIdx.x << 5, h0 = blockIdx.y << 5;
    const int x = threadIdx.x & 31, y = threadIdx.x >> 5;   // y in 0..7
    const long base = ((long)b * SRCc + s0) * Hc + h0;
#pragma unroll
    for (int j = 0; j < 4; j++) {
        int s = (y << 2) + j;
        float v = enc[base + (long)s * Hc + x];
        tile[s][x] = v;
        u16 h = f2bf(v);
        long o = base + (long)s * Hc + x;
        ehi[o] = h;
        elo[o] = f2bf(v - bf2f(h));
    }
    __syncthreads();
    const long tbase = ((long)b * Hc + h0) * SRCc + s0;
#pragma unroll
    for (int j = 0; j < 4; j++) {
        int hh = (y << 2) + j;
        float v = tile[x][hh];
        long o = tbase + (long)hh * SRCc + x;
        ethi[o] = f2bf(v);
    }
}

// ---------------- GEMM template ----------------
// C = sum_combos A_i [M][K] * B_j [N][K]^T, all bf16 row-major K-contiguous.
// 128x128 tile, BK=32, 256 threads = 4 waves (2x2), each wave 64x64 = 4x4 frags of 16x16x32.
// CFG 0: q GEMM        A={dec_hi,dec_lo} B={win_hi,win_lo} combos 3, K=512  -> split-store q
// CFG 1: align GEMM    A={q_hi,q_lo}     B={enc_hi,enc_lo} combos 3, K=512  -> f32 logits [t][b][s]
// CFG 2: PV GEMM       A={Pb}            B={encT_hi}       combos 1, K=2048 -> split-store ctx
// CFG 3: out GEMM      A=[ctx|dec] hi/lo B=[wA|wB] hi/lo   combos 3, K=1024 (ptr switch @512) -> tanh, [t][b][o]

struct GArgs {
    const u16* A0; const u16* A1;
    const u16* B0; const u16* B1;
    const u16* A2; const u16* A3;
    const u16* B2; const u16* B3;
    void* out0; void* out1;
};

__device__ __forceinline__ void gload_lds16(const u16* g, u16* l) {
    __builtin_amdgcn_global_load_lds((const __attribute__((address_space(1))) void*)g,
                                     (__attribute__((address_space(3))) void*)l, 16, 0, 0);
}

template <int CFG>
__global__ __launch_bounds__(256, 3) void gemm_bt(GArgs g) {
    constexpr int NA = (CFG == 2) ? 1 : 2;
    constexpr int NB = (CFG == 2) ? 1 : 2;
    constexpr int NC = (CFG == 2) ? 1 : 3;
    constexpr int K  = (CFG == 2) ? 2048 : (CFG == 3 ? 1024 : 512);
    constexpr int KST = (CFG == 3) ? 512 : K;   // row stride (CFG3 is two K=512 halves)
    constexpr int NT = NA + NB;

    __shared__ u16 lds[NT * 128 * 32];

    const int tid = threadIdx.x;
    const int lane = tid & 63;
    const int wave = tid >> 6;
    const int wm = wave >> 1;
    const int wn = wave & 1;

    int bz = 0, mt, nt;
    if constexpr (CFG == 1 || CFG == 2) { bz = blockIdx.z; mt = blockIdx.y; nt = blockIdx.x; }
    else { mt = blockIdx.x; nt = blockIdx.y; }

    const u16* apt[2][2];
    const u16* bpt[2][2];
    if constexpr (CFG == 1) {
        const long ao = (long)bz * TGTc * Hc, bo = (long)bz * SRCc * Hc;
        apt[0][0] = g.A0 + ao; apt[0][1] = g.A1 + ao;
        bpt[0][0] = g.B0 + bo; bpt[0][1] = g.B1 + bo;
    } else if constexpr (CFG == 2) {
        apt[0][0] = g.A0 + (long)bz * TGTc * SRCc;
        bpt[0][0] = g.B0 + (long)bz * Hc * SRCc;
    } else if constexpr (CFG == 3) {
        apt[0][0] = g.A0; apt[0][1] = g.A1; apt[1][0] = g.A2; apt[1][1] = g.A3;
        bpt[0][0] = g.B0; bpt[0][1] = g.B1; bpt[1][0] = g.B2; bpt[1][1] = g.B3;
    } else {
        apt[0][0] = g.A0; apt[0][1] = g.A1;
        bpt[0][0] = g.B0; bpt[0][1] = g.B1;
    }

    f32x4 acc[4][4];
#pragma unroll
    for (int mi = 0; mi < 4; mi++)
#pragma unroll
        for (int ni = 0; ni < 4; ni++)
            acc[mi][ni] = (f32x4){0.f, 0.f, 0.f, 0.f};

    const int arow0 = mt * 128;
    const int brow0 = nt * 128;

    constexpr int cAi[3] = {0, 0, 1};
    constexpr int cBi[3] = {0, 1, 0};

    // swizzled frag-read chunk: global (r, c=lane>>4) lives at LDS chunk r*4 + (c ^ (r&3));
    // r&3 == lane&3 for all frags (r = w*64 + f*16 + (lane&15))
    const int csw = (((lane >> 4) ^ (lane & 3)) << 3);

    for (int k0 = 0; k0 < K; k0 += 32) {
        int sel = 0, kk = k0;
        if constexpr (CFG == 3) { sel = k0 >> 9; kk = k0 & 511; }
        // stage NT tiles of 128x32 bf16 (8 KB each) via global_load_lds width 16
#pragma unroll
        for (int t = 0; t < NT; t++) {
            const u16* base = (t < NA) ? (apt[sel][t] + (long)arow0 * KST + kk)
                                       : (bpt[sel][t - NA] + (long)brow0 * KST + kk);
            u16* dstbase = &lds[t * 4096];
#pragma unroll
            for (int it = 0; it < 2; ++it) {
                int l = it * 256 + tid;
                int row = l >> 2;
                // source-XOR swizzle so that the linear LDS write lands data such that
                // frag reads (csw above) are 4-way instead of 8-way bank conflicted
                int kel = ((l & 3) ^ (row & 3)) << 3;
                // LDS dest must be wave-uniform: base + it*2048 + wave*512 (u16 units);
                // HW adds lane*16B. Global src is per-lane.
                gload_lds16(base + (long)row * KST + kel, dstbase + it * 2048 + wave * 512);
            }
        }
        __syncthreads();

        s16x8 af[NA][4];
        s16x8 bfr[NB][4];
#pragma unroll
        for (int i = 0; i < NA; i++)
#pragma unroll
            for (int f = 0; f < 4; f++) {
                int r = wm * 64 + f * 16 + (lane & 15);
                af[i][f] = *(const s16x8*)&lds[i * 4096 + r * 32 + csw];
            }
#pragma unroll
        for (int i = 0; i < NB; i++)
#pragma unroll
            for (int f = 0; f < 4; f++) {
                int r = wn * 64 + f * 16 + (lane & 15);
                bfr[i][f] = *(const s16x8*)&lds[(NA + i) * 4096 + r * 32 + csw];
            }

#pragma unroll
        for (int c = 0; c < NC; c++)
#pragma unroll
            for (int mi = 0; mi < 4; mi++)
#pragma unroll
                for (int ni = 0; ni < 4; ni++)
                    acc[mi][ni] = __builtin_amdgcn_mfma_f32_16x16x32_bf16(
                        af[cAi[c]][mi], bfr[cBi[c]][ni], acc[mi][ni], 0, 0, 0);
        __syncthreads();
    }

    // epilogue; C/D layout: col = lane&15, row = (lane>>4)*4 + j
    const int m0 = mt * 128 + wm * 64;
    const int n0 = nt * 128 + wn * 64;
    const int ln15 = lane & 15;
    const int rg = (lane >> 4) << 2;

#pragma unroll
    for (int mi = 0; mi < 4; mi++) {
#pragma unroll
        for (int ni = 0; ni < 4; ni++) {
            f32x4 v = acc[mi][ni];
            int n = n0 + ni * 16 + ln15;
#pragma unroll
            for (int j = 0; j < 4; j++) {
                int m = m0 + mi * 16 + rg + j;
                float x = v[j];
                if constexpr (CFG == 0) {
                    long idx = (long)m * Hc + n;
                    u16 h = f2bf(x);
                    ((u16*)g.out0)[idx] = h;
                    ((u16*)g.out1)[idx] = f2bf(x - bf2f(h));
                } else if constexpr (CFG == 1) {
                    ((float*)g.out0)[((long)m * Bc + bz) * SRCc + n] = x;
                } else if constexpr (CFG == 2) {
                    long idx = ((long)bz * TGTc + m) * Hc + n;
                    u16 h = f2bf(x);
                    ((u16*)g.out0)[idx] = h;
                    ((u16*)g.out1)[idx] = f2bf(x - bf2f(h));
                } else {
                    float th = tanhf(x);
                    int t = m & (TGTc - 1), b = m >> 9;
                    ((float*)g.out0)[((long)t * Bc + b) * Hc + n] = th;
                }
            }
        }
    }
}

// ---------------- softmax ----------------
// one block per (b,t) row of 2048; in-place on logits in d_out ([t][b][s]); also writes Pb bf16 [b][t][s]
__global__ __launch_bounds__(256) void softmax_k(float* __restrict__ align, u16* __restrict__ Pb,
                                                 const int* __restrict__ lens) {
    const int row = blockIdx.x;          // b*512 + t
    const int b = row >> 9, t = row & (TGTc - 1);
    float* p = align + ((long)t * Bc + b) * SRCc;
    u16* pb = Pb + ((long)b * TGTc + t) * SRCc;
    const int len = lens[b];
    const int tid = threadIdx.x;

    f32x4 v[2];
    float mx = -3.4e38f;
#pragma unroll
    for (int i = 0; i < 2; i++) {
        int s0 = i * 1024 + tid * 4;
        v[i] = *(const f32x4*)&p[s0];
#pragma unroll
        for (int j = 0; j < 4; j++) {
            if (s0 + j >= len) v[i][j] = -3.4e38f;
            mx = fmaxf(mx, v[i][j]);
        }
    }
#pragma unroll
    for (int o = 32; o >= 1; o >>= 1) mx = fmaxf(mx, __shfl_xor(mx, o));
    __shared__ float red[8];
    if ((tid & 63) == 0) red[tid >> 6] = mx;
    __syncthreads();
    mx = fmaxf(fmaxf(red[0], red[1]), fmaxf(red[2], red[3]));

    float sum = 0.f;
    f32x4 e[2];
#pragma unroll
    for (int i = 0; i < 2; i++) {
        int s0 = i * 1024 + tid * 4;
#pragma unroll
        for (int j = 0; j < 4; j++) {
            float ev = (s0 + j >= len) ? 0.f : __expf(v[i][j] - mx);
            e[i][j] = ev;
            sum += ev;
        }
    }
#pragma unroll
    for (int o = 32; o >= 1; o >>= 1) sum += __shfl_xor(sum, o);
    if ((tid & 63) == 0) red[4 + (tid >> 6)] = sum;
    __syncthreads();
    sum = (red[4] + red[5]) + (red[6] + red[7]);
    float inv = 1.f / sum;

#pragma unroll
    for (int i = 0; i < 2; i++) {
        int s0 = i * 1024 + tid * 4;
        f32x4 o4;
        u16x4 h4;
#pragma unroll
        for (int j = 0; j < 4; j++) {
            float pv = e[i][j] * inv;
            o4[j] = pv;
            h4[j] = f2bf(pv);
        }
        *(f32x4*)&p[s0] = o4;
        *(u16x4*)&pb[s0] = h4;
    }
}

// ---------------- launch ----------------

extern "C" void kernel_launch(void* const* d_in, const int* in_sizes, int n_in,
                              void* d_out, int out_size, void* d_ws, size_t ws_size,
                              hipStream_t stream) {
    const float* dec  = (const float*)d_in[0];
    const float* enc  = (const float*)d_in[1];
    const u32*   lenp = (const u32*)d_in[2];
    const float* win  = (const float*)d_in[3];
    const float* wout = (const float*)d_in[4];

    float* out_attn  = (float*)d_out;                          // [512][32][512]
    float* out_align = out_attn + (size_t)TGTc * Bc * Hc;      // [512][32][2048]

    char* w = (char*)d_ws;
    auto take = [&](size_t n) { char* p = w; w += (n + 255) & ~(size_t)255; return p; };
    int* lens      = (int*)take(256);
    u16* dec_hi    = (u16*)take((size_t)8388608 * 2);
    u16* dec_lo    = (u16*)take((size_t)8388608 * 2);
    u16* win_hi    = (u16*)take((size_t)262144 * 2);
    u16* win_lo    = (u16*)take((size_t)262144 * 2);
    u16* wA_hi     = (u16*)take((size_t)262144 * 2);
    u16* wA_lo     = (u16*)take((size_t)262144 * 2);
    u16* wB_hi     = (u16*)take((size_t)262144 * 2);
    u16* wB_lo     = (u16*)take((size_t)262144 * 2);
    u16* enc_hi    = (u16*)take((size_t)33554432 * 2);   // reused as Pb after K2
    u16* enc_lo    = (u16*)take((size_t)33554432 * 2);   // reused as ctx_hi/lo after K2
    u16* encT_hi   = (u16*)take((size_t)33554432 * 2);
    // aliases (lifetimes disjoint, same stream => ordered)
    u16* q_hi   = (u16*)out_attn;            // attn region free until final kernel
    u16* q_lo   = q_hi + 8388608;
    u16* Pb     = enc_hi;
    u16* ctx_hi = enc_lo;
    u16* ctx_lo = enc_lo + 8388608;
    (void)in_sizes; (void)n_in; (void)out_size; (void)ws_size;

    prep_len_k<<<1, 64, 0, stream>>>(lenp, lens);
    split_k<<<2048, 256, 0, stream>>>(dec, dec_hi, dec_lo, 8388608 / 4);
    split_k<<<256, 256, 0, stream>>>(win, win_hi, win_lo, 262144 / 4);
    split_wout_k<<<512, 256, 0, stream>>>(wout, wA_hi, wA_lo, wB_hi, wB_lo);
    prep_enc_k<<<dim3(64, 16, 32), 256, 0, stream>>>(enc, enc_hi, enc_lo, encT_hi);

    GArgs a1 = {};
    a1.A0 = dec_hi; a1.A1 = dec_lo; a1.B0 = win_hi; a1.B1 = win_lo;
    a1.out0 = q_hi; a1.out1 = q_lo;
    gemm_bt<0><<<dim3(128, 4, 1), 256, 0, stream>>>(a1);

    GArgs a2 = {};
    a2.A0 = q_hi; a2.A1 = q_lo; a2.B0 = enc_hi; a2.B1 = enc_lo;
    a2.out0 = out_align;
    gemm_bt<1><<<dim3(16, 4, 32), 256, 0, stream>>>(a2);   // x=nt, y=mt, z=b

    softmax_k<<<16384, 256, 0, stream>>>(out_align, Pb, lens);

    GArgs a4 = {};
    a4.A0 = Pb; a4.B0 = encT_hi;
    a4.out0 = ctx_hi; a4.out1 = ctx_lo;
    gemm_bt<2><<<dim3(4, 4, 32), 256, 0, stream>>>(a4);    // x=nt, y=mt, z=b

    GArgs a5 = {};
    a5.A0 = ctx_hi; a5.A1 = ctx_lo; a5.B0 = wA_hi; a5.B1 = wA_lo;
    a5.A2 = dec_hi; a5.A3 = dec_lo; a5.B2 = wB_hi; a5.B3 = wB_lo;
    a5.out0 = out_attn;
    gemm_bt<3><<<dim3(128, 4, 1), 256, 0, stream>>>(a5);
}

// Round 3
// 650.338 us; speedup vs baseline: 1.0530x; 1.0331x over previous
//
#include <hip/hip_runtime.h>

// Problem constants
#define Bc   32
#define TGTc 512
#define SRCc 2048
#define Hc   512

typedef unsigned short u16;
typedef unsigned int   u32;
typedef __attribute__((ext_vector_type(8))) short s16x8;
typedef __attribute__((ext_vector_type(4))) float f32x4;
typedef __attribute__((ext_vector_type(4))) unsigned short u16x4;

__device__ __forceinline__ u16 f2bf(float x) {
    u32 u = __float_as_uint(x);
    u32 r = (u + 0x7FFFu + ((u >> 16) & 1u)) >> 16;
    return (u16)r;
}
__device__ __forceinline__ float bf2f(u16 h) {
    return __uint_as_float(((u32)h) << 16);
}

// ---------------- prep kernels ----------------

// lengths may be int64 (jax x64) or int32; detect via high word of elem 0
__global__ void prep_len_k(const u32* __restrict__ raw, int* __restrict__ out) {
    int i = threadIdx.x;
    if (i >= Bc) return;
    bool is64 = (raw[1] == 0u);   // lengths >= 1024, so int32 path has raw[1] != 0
    out[i] = (int)(is64 ? raw[2 * i] : raw[i]);
}

// split fp32 -> bf16 hi + bf16 lo, vectorized x4
__global__ __launch_bounds__(256) void split_k(const float* __restrict__ in,
                                               u16* __restrict__ hi, u16* __restrict__ lo,
                                               int n4) {
    int stride = gridDim.x * 256;
    for (int i = blockIdx.x * 256 + threadIdx.x; i < n4; i += stride) {
        f32x4 x = ((const f32x4*)in)[i];
        u16x4 h, l;
#pragma unroll
        for (int j = 0; j < 4; j++) {
            u16 hb = f2bf(x[j]);
            h[j] = hb;
            l[j] = f2bf(x[j] - bf2f(hb));
        }
        ((u16x4*)hi)[i] = h;
        ((u16x4*)lo)[i] = l;
    }
}

// merged weight prep:
//   blocks [0,256):  W_in [512][512]   -> win_hi/lo
//   blocks [256,768): W_out [512][1024] -> wA half (cols 0..511) + wB half, hi/lo each
__global__ __launch_bounds__(256) void split_weights_k(const float* __restrict__ win,
                                                       const float* __restrict__ wout,
                                                       u16* __restrict__ wih, u16* __restrict__ wil,
                                                       u16* __restrict__ ah, u16* __restrict__ al,
                                                       u16* __restrict__ bh, u16* __restrict__ bl) {
    int blk = blockIdx.x;
    if (blk < 256) {
        int i = blk * 256 + threadIdx.x;      // over 512*512/4 float4s
        f32x4 x = ((const f32x4*)win)[i];
        u16x4 h, l;
#pragma unroll
        for (int j = 0; j < 4; j++) {
            u16 hb = f2bf(x[j]);
            h[j] = hb;
            l[j] = f2bf(x[j] - bf2f(hb));
        }
        ((u16x4*)wih)[i] = h;
        ((u16x4*)wil)[i] = l;
    } else {
        int i = (blk - 256) * 256 + threadIdx.x;   // over 512*1024/4 = 131072 float4s
        int o = i >> 8, kc = i & 255;
        f32x4 x = ((const f32x4*)wout)[i];
        u16x4 h, l;
#pragma unroll
        for (int j = 0; j < 4; j++) {
            u16 hb = f2bf(x[j]);
            h[j] = hb;
            l[j] = f2bf(x[j] - bf2f(hb));
        }
        int half = kc >> 7;
        int idx = o * 128 + (kc & 127);
        ((u16x4*)(half ? bh : ah))[idx] = h;
        ((u16x4*)(half ? bl : al))[idx] = l;
    }
}

// enc [B][SRC][H] fp32 -> enc_hi/lo [B][SRC][H] bf16 and encT_hi [B][H][SRC] bf16
// 64x64 tiles; f32x4 loads, u16x4 stores everywhere; stride-67 padded LDS transpose
__global__ __launch_bounds__(256) void prep_enc_v2(const float* __restrict__ enc,
                                                   u16* __restrict__ ehi, u16* __restrict__ elo,
                                                   u16* __restrict__ ethi) {
    __shared__ float tile[64][67];   // 67 mod 32 = 3 -> ~2-way on both phases
    const int b = blockIdx.z;
    const int s0 = blockIdx.x << 6, h0 = blockIdx.y << 6;
    const int t = threadIdx.x;
    const int si = t >> 4;           // 0..15
    const int h4 = (t & 15) << 2;    // 0,4,..,60
    const long base = ((long)b * SRCc + s0) * Hc + h0;
#pragma unroll
    for (int j = 0; j < 4; j++) {
        int s = si + j * 16;
        long o = base + (long)s * Hc + h4;
        f32x4 v = *(const f32x4*)&enc[o];
        tile[s][h4 + 0] = v[0];
        tile[s][h4 + 1] = v[1];
        tile[s][h4 + 2] = v[2];
        tile[s][h4 + 3] = v[3];
        u16x4 hh, ll;
#pragma unroll
        for (int k = 0; k < 4; k++) {
            u16 hb = f2bf(v[k]);
            hh[k] = hb;
            ll[k] = f2bf(v[k] - bf2f(hb));
        }
        ((u16x4*)ehi)[o >> 2] = hh;
        ((u16x4*)elo)[o >> 2] = ll;
    }
    __syncthreads();
    const int hi_ = t >> 4;          // 0..15
    const int s4 = (t & 15) << 2;    // 0,4,..,60
    const long tbase = ((long)b * Hc + h0) * SRCc + s0;
#pragma unroll
    for (int j = 0; j < 4; j++) {
        int h = hi_ + j * 16;
        u16x4 hh;
#pragma unroll
        for (int k = 0; k < 4; k++) hh[k] = f2bf(tile[s4 + k][h]);
        ((u16x4*)ethi)[(tbase + (long)h * SRCc + s4) >> 2] = hh;
    }
}

// ---------------- GEMM template ----------------
// C = sum_combos A_i [M][K] * B_j [N][K]^T, all bf16 row-major K-contiguous.
// 128x128 tile, BK=32, 256 threads = 4 waves (2x2), each wave 64x64 = 4x4 frags of 16x16x32.
// CFG 0: q GEMM        A={dec_hi,dec_lo} B={win_hi,win_lo} combos 3, K=512  -> split-store q
// CFG 1: align GEMM    A={q_hi,q_lo}     B={enc_hi,enc_lo} combos 3, K=512  -> f32 logits [t][b][s]
// CFG 2: PV GEMM       A={Pb}            B={encT_hi}       combos 1, K=2048 -> split-store ctx
// CFG 3: out GEMM      A=[ctx|dec] hi/lo B=[wA|wB] hi/lo   combos 3, K=1024 (ptr switch @512) -> tanh, [t][b][o]

struct GArgs {
    const u16* A0; const u16* A1;
    const u16* B0; const u16* B1;
    const u16* A2; const u16* A3;
    const u16* B2; const u16* B3;
    void* out0; void* out1;
};

__device__ __forceinline__ void gload_lds16(const u16* g, u16* l) {
    __builtin_amdgcn_global_load_lds((const __attribute__((address_space(1))) void*)g,
                                     (__attribute__((address_space(3))) void*)l, 16, 0, 0);
}

template <int CFG>
__global__ __launch_bounds__(256, 3) void gemm_bt(GArgs g) {
    constexpr int NA = (CFG == 2) ? 1 : 2;
    constexpr int NB = (CFG == 2) ? 1 : 2;
    constexpr int NC = (CFG == 2) ? 1 : 3;
    constexpr int K  = (CFG == 2) ? 2048 : (CFG == 3 ? 1024 : 512);
    constexpr int KST = (CFG == 3) ? 512 : K;   // row stride (CFG3 is two K=512 halves)
    constexpr int NT = NA + NB;

    __shared__ u16 lds[NT * 128 * 32];

    const int tid = threadIdx.x;
    const int lane = tid & 63;
    const int wave = tid >> 6;
    const int wm = wave >> 1;
    const int wn = wave & 1;

    int bz = 0, mt, nt;
    if constexpr (CFG == 1 || CFG == 2) { bz = blockIdx.z; mt = blockIdx.y; nt = blockIdx.x; }
    else { mt = blockIdx.x; nt = blockIdx.y; }

    const u16* apt[2][2];
    const u16* bpt[2][2];
    if constexpr (CFG == 1) {
        const long ao = (long)bz * TGTc * Hc, bo = (long)bz * SRCc * Hc;
        apt[0][0] = g.A0 + ao; apt[0][1] = g.A1 + ao;
        bpt[0][0] = g.B0 + bo; bpt[0][1] = g.B1 + bo;
    } else if constexpr (CFG == 2) {
        apt[0][0] = g.A0 + (long)bz * TGTc * SRCc;
        bpt[0][0] = g.B0 + (long)bz * Hc * SRCc;
    } else if constexpr (CFG == 3) {
        apt[0][0] = g.A0; apt[0][1] = g.A1; apt[1][0] = g.A2; apt[1][1] = g.A3;
        bpt[0][0] = g.B0; bpt[0][1] = g.B1; bpt[1][0] = g.B2; bpt[1][1] = g.B3;
    } else {
        apt[0][0] = g.A0; apt[0][1] = g.A1;
        bpt[0][0] = g.B0; bpt[0][1] = g.B1;
    }

    f32x4 acc[4][4];
#pragma unroll
    for (int mi = 0; mi < 4; mi++)
#pragma unroll
        for (int ni = 0; ni < 4; ni++)
            acc[mi][ni] = (f32x4){0.f, 0.f, 0.f, 0.f};

    const int arow0 = mt * 128;
    const int brow0 = nt * 128;

    constexpr int cAi[3] = {0, 0, 1};
    constexpr int cBi[3] = {0, 1, 0};

    for (int k0 = 0; k0 < K; k0 += 32) {
        int sel = 0, kk = k0;
        if constexpr (CFG == 3) { sel = k0 >> 9; kk = k0 & 511; }
        // stage NT tiles of 128x32 bf16 (8 KB each) via global_load_lds width 16
#pragma unroll
        for (int t = 0; t < NT; t++) {
            const u16* base = (t < NA) ? (apt[sel][t] + (long)arow0 * KST + kk)
                                       : (bpt[sel][t - NA] + (long)brow0 * KST + kk);
            u16* dstbase = &lds[t * 4096];
#pragma unroll
            for (int it = 0; it < 2; ++it) {
                int l = it * 256 + tid;
                int row = l >> 2;
                int kel = (l & 3) << 3;
                // LDS dest must be wave-uniform: base + it*2048 + wave*512 (u16 units);
                // HW adds lane*16B. Global src is per-lane.
                gload_lds16(base + (long)row * KST + kel, dstbase + it * 2048 + wave * 512);
            }
        }
        __syncthreads();

        s16x8 af[NA][4];
        s16x8 bfr[NB][4];
#pragma unroll
        for (int i = 0; i < NA; i++)
#pragma unroll
            for (int f = 0; f < 4; f++) {
                int r = wm * 64 + f * 16 + (lane & 15);
                af[i][f] = *(const s16x8*)&lds[i * 4096 + r * 32 + ((lane >> 4) << 3)];
            }
#pragma unroll
        for (int i = 0; i < NB; i++)
#pragma unroll
            for (int f = 0; f < 4; f++) {
                int r = wn * 64 + f * 16 + (lane & 15);
                bfr[i][f] = *(const s16x8*)&lds[(NA + i) * 4096 + r * 32 + ((lane >> 4) << 3)];
            }

#pragma unroll
        for (int c = 0; c < NC; c++)
#pragma unroll
            for (int mi = 0; mi < 4; mi++)
#pragma unroll
                for (int ni = 0; ni < 4; ni++)
                    acc[mi][ni] = __builtin_amdgcn_mfma_f32_16x16x32_bf16(
                        af[cAi[c]][mi], bfr[cBi[c]][ni], acc[mi][ni], 0, 0, 0);
        __syncthreads();
    }

    // epilogue; C/D layout: col = lane&15, row = (lane>>4)*4 + j
    const int m0 = mt * 128 + wm * 64;
    const int n0 = nt * 128 + wn * 64;
    const int ln15 = lane & 15;
    const int rg = (lane >> 4) << 2;

#pragma unroll
    for (int mi = 0; mi < 4; mi++) {
#pragma unroll
        for (int ni = 0; ni < 4; ni++) {
            f32x4 v = acc[mi][ni];
            int n = n0 + ni * 16 + ln15;
#pragma unroll
            for (int j = 0; j < 4; j++) {
                int m = m0 + mi * 16 + rg + j;
                float x = v[j];
                if constexpr (CFG == 0) {
                    long idx = (long)m * Hc + n;
                    u16 h = f2bf(x);
                    ((u16*)g.out0)[idx] = h;
                    ((u16*)g.out1)[idx] = f2bf(x - bf2f(h));
                } else if constexpr (CFG == 1) {
                    ((float*)g.out0)[((long)m * Bc + bz) * SRCc + n] = x;
                } else if constexpr (CFG == 2) {
                    long idx = ((long)bz * TGTc + m) * Hc + n;
                    u16 h = f2bf(x);
                    ((u16*)g.out0)[idx] = h;
                    ((u16*)g.out1)[idx] = f2bf(x - bf2f(h));
                } else {
                    float th = tanhf(x);
                    int t = m & (TGTc - 1), b = m >> 9;
                    ((float*)g.out0)[((long)t * Bc + b) * Hc + n] = th;
                }
            }
        }
    }
}

// ---------------- softmax ----------------
// one block per (b,t) row of 2048; in-place on logits in d_out ([t][b][s]); also writes Pb bf16 [b][t][s]
__global__ __launch_bounds__(256) void softmax_k(float* __restrict__ align, u16* __restrict__ Pb,
                                                 const int* __restrict__ lens) {
    const int row = blockIdx.x;          // b*512 + t
    const int b = row >> 9, t = row & (TGTc - 1);
    float* p = align + ((long)t * Bc + b) * SRCc;
    u16* pb = Pb + ((long)b * TGTc + t) * SRCc;
    const int len = lens[b];
    const int tid = threadIdx.x;

    f32x4 v[2];
    float mx = -3.4e38f;
#pragma unroll
    for (int i = 0; i < 2; i++) {
        int s0 = i * 1024 + tid * 4;
        v[i] = *(const f32x4*)&p[s0];
#pragma unroll
        for (int j = 0; j < 4; j++) {
            if (s0 + j >= len) v[i][j] = -3.4e38f;
            mx = fmaxf(mx, v[i][j]);
        }
    }
#pragma unroll
    for (int o = 32; o >= 1; o >>= 1) mx = fmaxf(mx, __shfl_xor(mx, o));
    __shared__ float red[8];
    if ((tid & 63) == 0) red[tid >> 6] = mx;
    __syncthreads();
    mx = fmaxf(fmaxf(red[0], red[1]), fmaxf(red[2], red[3]));

    float sum = 0.f;
    f32x4 e[2];
#pragma unroll
    for (int i = 0; i < 2; i++) {
        int s0 = i * 1024 + tid * 4;
#pragma unroll
        for (int j = 0; j < 4; j++) {
            float ev = (s0 + j >= len) ? 0.f : __expf(v[i][j] - mx);
            e[i][j] = ev;
            sum += ev;
        }
    }
#pragma unroll
    for (int o = 32; o >= 1; o >>= 1) sum += __shfl_xor(sum, o);
    if ((tid & 63) == 0) red[4 + (tid >> 6)] = sum;
    __syncthreads();
    sum = (red[4] + red[5]) + (red[6] + red[7]);
    float inv = 1.f / sum;

#pragma unroll
    for (int i = 0; i < 2; i++) {
        int s0 = i * 1024 + tid * 4;
        f32x4 o4;
        u16x4 h4;
#pragma unroll
        for (int j = 0; j < 4; j++) {
            float pv = e[i][j] * inv;
            o4[j] = pv;
            h4[j] = f2bf(pv);
        }
        *(f32x4*)&p[s0] = o4;
        *(u16x4*)&pb[s0] = h4;
    }
}

// ---------------- launch ----------------

extern "C" void kernel_launch(void* const* d_in, const int* in_sizes, int n_in,
                              void* d_out, int out_size, void* d_ws, size_t ws_size,
                              hipStream_t stream) {
    const float* dec  = (const float*)d_in[0];
    const float* enc  = (const float*)d_in[1];
    const u32*   lenp = (const u32*)d_in[2];
    const float* win  = (const float*)d_in[3];
    const float* wout = (const float*)d_in[4];

    float* out_attn  = (float*)d_out;                          // [512][32][512]
    float* out_align = out_attn + (size_t)TGTc * Bc * Hc;      // [512][32][2048]

    char* w = (char*)d_ws;
    auto take = [&](size_t n) { char* p = w; w += (n + 255) & ~(size_t)255; return p; };
    int* lens      = (int*)take(256);
    u16* dec_hi    = (u16*)take((size_t)8388608 * 2);
    u16* dec_lo    = (u16*)take((size_t)8388608 * 2);
    u16* win_hi    = (u16*)take((size_t)262144 * 2);
    u16* win_lo    = (u16*)take((size_t)262144 * 2);
    u16* wA_hi     = (u16*)take((size_t)262144 * 2);
    u16* wA_lo     = (u16*)take((size_t)262144 * 2);
    u16* wB_hi     = (u16*)take((size_t)262144 * 2);
    u16* wB_lo     = (u16*)take((size_t)262144 * 2);
    u16* enc_hi    = (u16*)take((size_t)33554432 * 2);   // reused as Pb after align GEMM
    u16* enc_lo    = (u16*)take((size_t)33554432 * 2);   // reused as ctx_hi/lo after PV
    u16* encT_hi   = (u16*)take((size_t)33554432 * 2);
    // aliases (lifetimes disjoint, same stream => ordered)
    u16* q_hi   = (u16*)out_attn;            // attn region free until final kernel
    u16* q_lo   = q_hi + 8388608;
    u16* Pb     = enc_hi;
    u16* ctx_hi = enc_lo;
    u16* ctx_lo = enc_lo + 8388608;
    (void)in_sizes; (void)n_in; (void)out_size; (void)ws_size;

    prep_len_k<<<1, 64, 0, stream>>>(lenp, lens);
    split_k<<<2048, 256, 0, stream>>>(dec, dec_hi, dec_lo, 8388608 / 4);
    split_weights_k<<<768, 256, 0, stream>>>(win, wout, win_hi, win_lo,
                                             wA_hi, wA_lo, wB_hi, wB_lo);
    prep_enc_v2<<<dim3(32, 8, 32), 256, 0, stream>>>(enc, enc_hi, enc_lo, encT_hi);

    GArgs a1 = {};
    a1.A0 = dec_hi; a1.A1 = dec_lo; a1.B0 = win_hi; a1.B1 = win_lo;
    a1.out0 = q_hi; a1.out1 = q_lo;
    gemm_bt<0><<<dim3(128, 4, 1), 256, 0, stream>>>(a1);

    GArgs a2 = {};
    a2.A0 = q_hi; a2.A1 = q_lo; a2.B0 = enc_hi; a2.B1 = enc_lo;
    a2.out0 = out_align;
    gemm_bt<1><<<dim3(16, 4, 32), 256, 0, stream>>>(a2);   // x=nt, y=mt, z=b

    softmax_k<<<16384, 256, 0, stream>>>(out_align, Pb, lens);

    GArgs a4 = {};
    a4.A0 = Pb; a4.B0 = encT_hi;
    a4.out0 = ctx_hi; a4.out1 = ctx_lo;
    gemm_bt<2><<<dim3(4, 4, 32), 256, 0, stream>>>(a4);    // x=nt, y=mt, z=b

    GArgs a5 = {};
    a5.A0 = ctx_hi; a5.A1 = ctx_lo; a5.B0 = wA_hi; a5.B1 = wA_lo;
    a5.A2 = dec_hi; a5.A3 = dec_lo; a5.B2 = wB_hi; a5.B3 = wB_lo;
    a5.out0 = out_attn;
    gemm_bt<3><<<dim3(128, 4, 1), 256, 0, stream>>>(a5);
}